// Round 19
// baseline (357.340 us; speedup 1.0000x reference)
//
#include <hip/hip_runtime.h>
#include <cstdint>
#include <cstddef>

#define B_    4
#define L_    1024
#define DIM_  256
#define DI_   512
#define NTOK  (B_*L_)
#define NC    16
#define CL    (L_/NC)      // 64

__device__ __forceinline__ float siluf_(float x){ return x / (1.0f + __expf(-x)); }
__device__ __forceinline__ float softplusf_(float x){
  return (x > 15.0f) ? x : log1pf(__expf(x));
}

// ---------- LN stats (blocks 0..1023) + A_log structure check (block 1024) ----------
__global__ __launch_bounds__(256) void k_ln_check(const float* __restrict__ x,
    float* __restrict__ stats, const float* __restrict__ A_log,
    int* __restrict__ flag){
  if (blockIdx.x == NTOK/4){
    __shared__ int s_ok;
    int tid = threadIdx.x;
    if (tid == 0) s_ok = 1;
    __syncthreads();
    int ok = 1;
    for (int i = tid; i < 512 * 64; i += 256){
      int n = i & 63;
      float ref = logf((float)(n + 1));
      float v = A_log[i];
      if (fabsf(v - ref) > 1e-5f * fmaxf(1.0f, fabsf(ref))) ok = 0;
    }
    if (!ok) atomicAnd(&s_ok, 0);
    __syncthreads();
    if (tid == 0) *flag = s_ok;
    return;
  }
  int tok  = blockIdx.x * 4 + (threadIdx.x >> 6);
  int lane = threadIdx.x & 63;
  float4 v = *(const float4*)(x + (size_t)tok * DIM_ + lane * 4);
  float s  = v.x + v.y + v.z + v.w;
  float sq = v.x*v.x + v.y*v.y + v.z*v.z + v.w*v.w;
  #pragma unroll
  for (int off = 32; off; off >>= 1){
    s  += __shfl_xor(s,  off, 64);
    sq += __shfl_xor(sq, off, 64);
  }
  if (lane == 0){
    float mu = s * (1.0f / DIM_);
    stats[tok*2]   = mu;
    stats[tok*2+1] = rsqrtf(sq * (1.0f / DIM_) - mu*mu + 1e-5f);
  }
}

// ---------- GEMM1 (LN fused): xz[m,n] = LN(x)[m,:] . W_in[n,:]  (4096x1024x256) ----------
__global__ __launch_bounds__(256) void k_gemm1(const float* __restrict__ x,
    const float* __restrict__ stats, const float* __restrict__ gamma,
    const float* __restrict__ beta, const float* __restrict__ Win,
    float* __restrict__ xz){
  __shared__ float As[16][64];
  __shared__ float Bs[16][64];
  int tid = threadIdx.x;
  int mBase = blockIdx.y * 64;
  int nBase = blockIdx.x * 64;
  int tx = tid & 15, ty = tid >> 4;
  int am = tid >> 2, ak = (tid & 3) << 2;
  float mu = stats[(mBase+am)*2], rs = stats[(mBase+am)*2+1];
  float acc[4][4] = {};
  for (int kt = 0; kt < 256; kt += 16){
    float4 av = *(const float4*)(x   + (size_t)(mBase+am)*256 + kt + ak);
    float4 bv = *(const float4*)(Win + (size_t)(nBase+am)*256 + kt + ak);
    float4 gv = *(const float4*)(gamma + kt + ak);
    float4 be = *(const float4*)(beta  + kt + ak);
    As[ak+0][am] = (av.x - mu) * rs * gv.x + be.x;
    As[ak+1][am] = (av.y - mu) * rs * gv.y + be.y;
    As[ak+2][am] = (av.z - mu) * rs * gv.z + be.z;
    As[ak+3][am] = (av.w - mu) * rs * gv.w + be.w;
    Bs[ak+0][am]=bv.x; Bs[ak+1][am]=bv.y; Bs[ak+2][am]=bv.z; Bs[ak+3][am]=bv.w;
    __syncthreads();
    #pragma unroll
    for (int kk = 0; kk < 16; kk++){
      float4 a = *(const float4*)&As[kk][ty*4];
      float4 b = *(const float4*)&Bs[kk][tx*4];
      float ar[4] = {a.x,a.y,a.z,a.w}, br[4] = {b.x,b.y,b.z,b.w};
      #pragma unroll
      for (int i=0;i<4;i++)
        #pragma unroll
        for (int j=0;j<4;j++)
          acc[i][j] += ar[i]*br[j];
    }
    __syncthreads();
  }
  #pragma unroll
  for (int i=0;i<4;i++){
    float4 o = make_float4(acc[i][0],acc[i][1],acc[i][2],acc[i][3]);
    *(float4*)(xz + (size_t)(mBase+ty*4+i)*1024 + nBase + tx*4) = o;
  }
}

// ---------- causal depthwise conv (w=4) + SiLU ----------
__global__ __launch_bounds__(256) void k_conv(const float* __restrict__ xz,
    const float* __restrict__ cw, const float* __restrict__ cb,
    float* __restrict__ uc){
  int g = blockIdx.x * 256 + threadIdx.x;
  int d = g & 511;
  int tok = g >> 9;
  int t = tok & (L_ - 1);
  float w0 = cw[d*4+0], w1 = cw[d*4+1], w2 = cw[d*4+2], w3 = cw[d*4+3];
  const float* up = xz + (size_t)tok * 1024 + d;
  float acc = cb[d] + w3 * up[0];
  if (t >= 1) acc += w2 * up[-1 * 1024];
  if (t >= 2) acc += w1 * up[-2 * 1024];
  if (t >= 3) acc += w0 * up[-3 * 1024];
  uc[g] = siluf_(acc);
}

// ---------- GEMM2 + fused dt: block = 320 thr (80 cols x 4 rows); grid 1024 ----------
__global__ __launch_bounds__(320) void k_gemm2(const float* __restrict__ uc,
    const float* __restrict__ Wx, const float* __restrict__ Wdt,
    const float* __restrict__ bdt, float* __restrict__ dbl,
    float* __restrict__ dt){
  __shared__ float As[4 * 516];
  __shared__ float sdt[4][16];
  int tid = threadIdx.x;
  int mBase = blockIdx.x * 4;
  for (int idx = tid * 4; idx < 4 * 512; idx += 320 * 4){
    int r = idx >> 9, k = idx & 511;
    *(float4*)&As[r * 516 + k] = *(const float4*)(uc + (size_t)(mBase + r) * 512 + k);
  }
  __syncthreads();
  int n = tid >> 2;    // 0..79
  int r = tid & 3;     // 0..3
  const float* arow = &As[r * 516];
  const float* wp = Wx + (size_t)n * 512;
  float acc = 0.f;
  #pragma unroll 8
  for (int k4 = 0; k4 < 512; k4 += 4){
    float4 a = *(const float4*)&arow[k4];
    float4 w = *(const float4*)(wp + k4);
    acc += a.x*w.x + a.y*w.y + a.z*w.z + a.w*w.w;
  }
  dbl[(size_t)(mBase + r) * 80 + n] = acc;
  if (n < 16) sdt[r][n] = acc;
  __syncthreads();
  for (int i = tid; i < 4 * 512; i += 320){
    int rr = i >> 9, d = i & 511;
    float a2 = bdt[d];
    const float* wd = Wdt + d * 16;
    #pragma unroll
    for (int k = 0; k < 16; k++)
      a2 += sdt[rr][k] * wd[k];
    dt[(size_t)(mBase + rr) * 512 + d] = softplusf_(a2);
  }
}

// ---------- scan pass A: batch 8; lane owns 8 states of 1 channel; dual-path exp ----------
__global__ __launch_bounds__(256, 4) void k_scanA(const float* __restrict__ dt,
    const float* __restrict__ uc, const float* __restrict__ dbl,
    const float* __restrict__ A_log, const int* __restrict__ flagp,
    float* __restrict__ hseg, float* __restrict__ S){
  int gw   = (blockIdx.x * 256 + threadIdx.x) >> 6;
  int lane = threadIdx.x & 63;
  int dsub = lane & 7, ngrp = lane >> 3;
  int grp = gw & 255;
  int c   = gw >> 8;
  int ch  = grp * 8 + dsub;
  int b = ch >> 9, d = ch & 511;
  int fast = *flagp;
  const float* dtp = dt  + (size_t)b * L_ * 512 + d;
  const float* ucp = uc  + (size_t)b * L_ * 512 + d;
  const float* Bp  = dbl + (size_t)b * L_ * 80  + 16 + ngrp*8;
  float h[8] = {};
  float Ssum = 0.f;
  int tbeg = c * CL;
  float st1 = (float)(ngrp * 8 + 1);
  float Aa[8];
  if (!fast){
    float4 a0 = *(const float4*)(A_log + (size_t)d*64 + ngrp*8);
    float4 a1 = *(const float4*)(A_log + (size_t)d*64 + ngrp*8 + 4);
    Aa[0]=-__expf(a0.x); Aa[1]=-__expf(a0.y); Aa[2]=-__expf(a0.z); Aa[3]=-__expf(a0.w);
    Aa[4]=-__expf(a1.x); Aa[5]=-__expf(a1.y); Aa[6]=-__expf(a1.z); Aa[7]=-__expf(a1.w);
  }
  for (int t0 = tbeg; t0 < tbeg + CL; t0 += 8){
    float dt8[8], u8[8], Bv[8][8];
    #pragma unroll
    for (int j = 0; j < 8; j++){
      dt8[j] = dtp[(size_t)(t0+j) * 512];
      u8[j]  = ucp[(size_t)(t0+j) * 512];
      *(float4*)&Bv[j][0] = *(const float4*)(Bp + (size_t)(t0+j)*80);
      *(float4*)&Bv[j][4] = *(const float4*)(Bp + (size_t)(t0+j)*80 + 4);
    }
    if (fast){
      #pragma unroll
      for (int j = 0; j < 8; j++){
        float sc = dt8[j] * u8[j];
        Ssum += dt8[j];
        float e1 = __expf(-dt8[j]);
        float dA = __expf(-dt8[j] * st1);
        #pragma unroll
        for (int i = 0; i < 8; i++){
          h[i] = dA * h[i] + sc * Bv[j][i];
          dA *= e1;
        }
      }
    } else {
      #pragma unroll
      for (int j = 0; j < 8; j++){
        float sc = dt8[j] * u8[j];
        Ssum += dt8[j];
        #pragma unroll
        for (int i = 0; i < 8; i++)
          h[i] = __expf(dt8[j] * Aa[i]) * h[i] + sc * Bv[j][i];
      }
    }
  }
  float* hp = hseg + ((size_t)(c * 2048 + ch)) * 64 + ngrp*8;
  *(float4*)hp     = make_float4(h[0],h[1],h[2],h[3]);
  *(float4*)(hp+4) = make_float4(h[4],h[5],h[6],h[7]);
  if (ngrp == 0) S[c * 2048 + ch] = Ssum;
}

// ---------- scan pass B: sequential chunk combine, IN-PLACE ----------
__global__ __launch_bounds__(256) void k_scanB(float* __restrict__ hseg,
    const float* __restrict__ S, const float* __restrict__ A_log,
    const int* __restrict__ flagp){
  int ch   = (blockIdx.x * 256 + threadIdx.x) >> 6;
  int lane = threadIdx.x & 63;
  int d = ch & 511;
  int fast = *flagp;
  float A = fast ? -(float)(lane + 1) : -__expf(A_log[(size_t)d * 64 + lane]);
  float hc = 0.f;
  #pragma unroll
  for (int c = 0; c < NC; c++){
    size_t idx = ((size_t)(c * 2048 + ch)) * 64 + lane;
    float hf = hseg[idx];
    hseg[idx] = hc;
    float Sv = S[c * 2048 + ch];
    hc = hf + __expf(A * Sv) * hc;
  }
}

// ---------- scan pass C: batch 4; rescan from h_in; dual-path exp; butterfly ----------
__global__ __launch_bounds__(256, 4) void k_scanC(const float* __restrict__ dt,
    const float* __restrict__ uc, const float* __restrict__ dbl,
    const float* __restrict__ C_SA, const float* __restrict__ A_log,
    const int* __restrict__ flagp,
    const float* __restrict__ hin, float* __restrict__ ys){
  int gw   = (blockIdx.x * 256 + threadIdx.x) >> 6;
  int lane = threadIdx.x & 63;
  int dsub = lane & 7, ngrp = lane >> 3;
  int grp = gw & 255;
  int c   = gw >> 8;
  int ch  = grp * 8 + dsub;
  int b = ch >> 9, d = ch & 511;
  int fast = *flagp;
  const float* dtp = dt   + (size_t)b * L_ * 512 + d;
  const float* ucp = uc   + (size_t)b * L_ * 512 + d;
  const float* Bp  = dbl  + (size_t)b * L_ * 80  + 16 + ngrp*8;
  const float* Cp  = C_SA + (size_t)b * L_ * 64  + ngrp*8;
  float*       yw  = ys   + (size_t)b * L_ * 512 + d;
  float h[8];
  {
    const float* hp = hin + ((size_t)(c * 2048 + ch)) * 64 + ngrp*8;
    float4 h0 = *(const float4*)hp;
    float4 h1 = *(const float4*)(hp + 4);
    h[0]=h0.x; h[1]=h0.y; h[2]=h0.z; h[3]=h0.w;
    h[4]=h1.x; h[5]=h1.y; h[6]=h1.z; h[7]=h1.w;
  }
  int tbeg = c * CL;
  float st1 = (float)(ngrp * 8 + 1);
  float Aa[8];
  if (!fast){
    float4 a0 = *(const float4*)(A_log + (size_t)d*64 + ngrp*8);
    float4 a1 = *(const float4*)(A_log + (size_t)d*64 + ngrp*8 + 4);
    Aa[0]=-__expf(a0.x); Aa[1]=-__expf(a0.y); Aa[2]=-__expf(a0.z); Aa[3]=-__expf(a0.w);
    Aa[4]=-__expf(a1.x); Aa[5]=-__expf(a1.y); Aa[6]=-__expf(a1.z); Aa[7]=-__expf(a1.w);
  }
  for (int t0 = tbeg; t0 < tbeg + CL; t0 += 4){
    float dt4[4], u4[4], Bv[4][8], Cv[4][8];
    #pragma unroll
    for (int j = 0; j < 4; j++){
      dt4[j] = dtp[(size_t)(t0+j) * 512];
      u4[j]  = ucp[(size_t)(t0+j) * 512];
      *(float4*)&Bv[j][0] = *(const float4*)(Bp + (size_t)(t0+j)*80);
      *(float4*)&Bv[j][4] = *(const float4*)(Bp + (size_t)(t0+j)*80 + 4);
      *(float4*)&Cv[j][0] = *(const float4*)(Cp + (size_t)(t0+j)*64);
      *(float4*)&Cv[j][4] = *(const float4*)(Cp + (size_t)(t0+j)*64 + 4);
    }
    float yp[4];
    #pragma unroll
    for (int j = 0; j < 4; j++){
      float sc = dt4[j] * u4[j];
      float y = 0.f;
      if (fast){
        float e1 = __expf(-dt4[j]);
        float dA = __expf(-dt4[j] * st1);
        #pragma unroll
        for (int i = 0; i < 8; i++){
          h[i] = dA * h[i] + sc * Bv[j][i];
          y += h[i] * Cv[j][i];
          dA *= e1;
        }
      } else {
        #pragma unroll
        for (int i = 0; i < 8; i++){
          h[i] = __expf(dt4[j] * Aa[i]) * h[i] + sc * Bv[j][i];
          y += h[i] * Cv[j][i];
        }
      }
      yp[j] = y;
    }
    #pragma unroll
    for (int off = 8; off < 64; off <<= 1){
      #pragma unroll
      for (int j = 0; j < 4; j++)
        yp[j] += __shfl_xor(yp[j], off, 64);
    }
    if (ngrp == 0){
      #pragma unroll
      for (int j = 0; j < 4; j++)
        yw[(size_t)(t0+j) * 512] = yp[j];
    }
  }
}

// ---------- GEMM3 (gate fused): 64x64 tiles ----------
__global__ __launch_bounds__(256) void k_gemm3(const float* __restrict__ ys,
    const float* __restrict__ uc, const float* __restrict__ xz,
    const float* __restrict__ Dp, const float* __restrict__ Wout,
    float* __restrict__ out){
  __shared__ float As[16][64];
  __shared__ float Bs[16][64];
  int tid = threadIdx.x;
  int mBase = blockIdx.y * 64;
  int nBase = blockIdx.x * 64;
  int tx = tid & 15, ty = tid >> 4;
  int am = tid >> 2, ak = (tid & 3) << 2;
  float acc[4][4] = {};
  for (int kt = 0; kt < 512; kt += 16){
    int m = mBase + am;
    float4 yv = *(const float4*)(ys + (size_t)m*512 + kt + ak);
    float4 uv = *(const float4*)(uc + (size_t)m*512 + kt + ak);
    float4 zv = *(const float4*)(xz + (size_t)m*1024 + 512 + kt + ak);
    float4 dv = *(const float4*)(Dp + kt + ak);
    float4 bv = *(const float4*)(Wout + (size_t)(nBase+am)*512 + kt + ak);
    As[ak+0][am] = (yv.x + uv.x*dv.x) * siluf_(zv.x);
    As[ak+1][am] = (yv.y + uv.y*dv.y) * siluf_(zv.y);
    As[ak+2][am] = (yv.z + uv.z*dv.z) * siluf_(zv.z);
    As[ak+3][am] = (yv.w + uv.w*dv.w) * siluf_(zv.w);
    Bs[ak+0][am]=bv.x; Bs[ak+1][am]=bv.y; Bs[ak+2][am]=bv.z; Bs[ak+3][am]=bv.w;
    __syncthreads();
    #pragma unroll
    for (int kk=0;kk<16;kk++){
      float4 a = *(const float4*)&As[kk][ty*4];
      float4 b = *(const float4*)&Bs[kk][tx*4];
      float ar[4] = {a.x,a.y,a.z,a.w}, br[4] = {b.x,b.y,b.z,b.w};
      #pragma unroll
      for (int i=0;i<4;i++)
        #pragma unroll
        for (int j=0;j<4;j++)
          acc[i][j] += ar[i]*br[j];
    }
    __syncthreads();
  }
  #pragma unroll
  for (int i=0;i<4;i++){
    float4 o = make_float4(acc[i][0],acc[i][1],acc[i][2],acc[i][3]);
    *(float4*)(out + (size_t)(mBase+ty*4+i)*256 + nBase + tx*4) = o;
  }
}

extern "C" void kernel_launch(void* const* d_in, const int* in_sizes, int n_in,
                              void* d_out, int out_size, void* d_ws, size_t ws_size,
                              hipStream_t stream) {
  const float* x      = (const float*)d_in[0];
  const float* C_SA   = (const float*)d_in[1];
  const float* gamma  = (const float*)d_in[2];
  const float* beta   = (const float*)d_in[3];
  const float* W_in   = (const float*)d_in[4];
  const float* conv_w = (const float*)d_in[5];
  const float* conv_b = (const float*)d_in[6];
  const float* W_x    = (const float*)d_in[7];
  const float* W_dt   = (const float*)d_in[8];
  const float* b_dt   = (const float*)d_in[9];
  const float* A_log  = (const float*)d_in[10];
  const float* Dw     = (const float*)d_in[11];
  const float* W_out  = (const float*)d_in[12];
  float* out = (float*)d_out;

  float* ws    = (float*)d_ws;
  float* stats = ws;                        // 8192 used
  int*   flag  = (int*)(ws + 8192);
  float* xz    = ws    + 16384;             // 4194304
  float* uc    = xz    + 4194304;           // 2097152
  float* dbl   = uc    + 2097152;           // 327680
  float* dtb   = dbl   + 327680;            // 2097152
  float* hseg  = dtb   + 2097152;           // NC*131072 = 2097152 (doubles as hin)
  float* S     = hseg  + 2097152;           // 32768
  float* ysb   = S     + 32768;             // 2097152

  k_ln_check<<<NTOK/4 + 1, 256, 0, stream>>>(x, stats, A_log, flag);
  k_gemm1<<<dim3(16, 64), 256, 0, stream>>>(x, stats, gamma, beta, W_in, xz);
  k_conv <<<(NTOK*512)/256, 256, 0, stream>>>(xz, conv_w, conv_b, uc);
  k_gemm2<<<1024, 320, 0, stream>>>(uc, W_x, W_dt, b_dt, dbl, dtb);
  k_scanA<<<NC*64, 256, 0, stream>>>(dtb, uc, dbl, A_log, flag, hseg, S);
  k_scanB<<<512, 256, 0, stream>>>(hseg, S, A_log, flag);
  k_scanC<<<NC*64, 256, 0, stream>>>(dtb, uc, dbl, C_SA, A_log, flag, hseg, ysb);
  k_gemm3<<<dim3(4, 64), 256, 0, stream>>>(ysb, uc, xz, Dw, W_out, out);
}

// Round 20
// 262.248 us; speedup vs baseline: 1.3626x; 1.3626x over previous
//
#include <hip/hip_runtime.h>
#include <cstdint>
#include <cstddef>

#define B_    4
#define L_    1024
#define DIM_  256
#define DI_   512
#define NTOK  (B_*L_)
#define NC    16
#define CL    (L_/NC)      // 64

__device__ __forceinline__ float siluf_(float x){ return x / (1.0f + __expf(-x)); }
__device__ __forceinline__ float softplusf_(float x){
  return (x > 15.0f) ? x : log1pf(__expf(x));
}

// ---------- verify A_log[d][n] == log(n+1) for all d; flag=1 if structured ----------
__global__ __launch_bounds__(1024) void k_check(const float* __restrict__ A_log,
    int* __restrict__ flag){
  __shared__ int s_ok;
  int tid = threadIdx.x;
  if (tid == 0) s_ok = 1;
  __syncthreads();
  int ok = 1;
  for (int i = tid; i < 512 * 64; i += 1024){
    int n = i & 63;
    float ref = logf((float)(n + 1));
    float v = A_log[i];
    if (fabsf(v - ref) > 1e-5f * fmaxf(1.0f, fabsf(ref))) ok = 0;
  }
  if (!ok) atomicAnd(&s_ok, 0);
  __syncthreads();
  if (tid == 0) *flag = s_ok;
}

// ---------- LN stats: one wave per token ----------
__global__ __launch_bounds__(256) void k_ln_stats(const float* __restrict__ x,
    float* __restrict__ stats){
  int tok  = blockIdx.x * 4 + (threadIdx.x >> 6);
  int lane = threadIdx.x & 63;
  float4 v = *(const float4*)(x + (size_t)tok * DIM_ + lane * 4);
  float s  = v.x + v.y + v.z + v.w;
  float sq = v.x*v.x + v.y*v.y + v.z*v.z + v.w*v.w;
  #pragma unroll
  for (int off = 32; off; off >>= 1){
    s  += __shfl_xor(s,  off, 64);
    sq += __shfl_xor(sq, off, 64);
  }
  if (lane == 0){
    float mu = s * (1.0f / DIM_);
    stats[tok*2]   = mu;
    stats[tok*2+1] = rsqrtf(sq * (1.0f / DIM_) - mu*mu + 1e-5f);
  }
}

// ---------- GEMM1 (LN fused): xz[m,n] = LN(x)[m,:] . W_in[n,:]  (4096x1024x256) ----------
__global__ __launch_bounds__(256) void k_gemm1(const float* __restrict__ x,
    const float* __restrict__ stats, const float* __restrict__ gamma,
    const float* __restrict__ beta, const float* __restrict__ Win,
    float* __restrict__ xz){
  __shared__ float As[16][64];
  __shared__ float Bs[16][64];
  int tid = threadIdx.x;
  int mBase = blockIdx.y * 64;
  int nBase = blockIdx.x * 64;
  int tx = tid & 15, ty = tid >> 4;
  int am = tid >> 2, ak = (tid & 3) << 2;
  float mu = stats[(mBase+am)*2], rs = stats[(mBase+am)*2+1];
  float acc[4][4] = {};
  for (int kt = 0; kt < 256; kt += 16){
    float4 av = *(const float4*)(x   + (size_t)(mBase+am)*256 + kt + ak);
    float4 bv = *(const float4*)(Win + (size_t)(nBase+am)*256 + kt + ak);
    float4 gv = *(const float4*)(gamma + kt + ak);
    float4 be = *(const float4*)(beta  + kt + ak);
    As[ak+0][am] = (av.x - mu) * rs * gv.x + be.x;
    As[ak+1][am] = (av.y - mu) * rs * gv.y + be.y;
    As[ak+2][am] = (av.z - mu) * rs * gv.z + be.z;
    As[ak+3][am] = (av.w - mu) * rs * gv.w + be.w;
    Bs[ak+0][am]=bv.x; Bs[ak+1][am]=bv.y; Bs[ak+2][am]=bv.z; Bs[ak+3][am]=bv.w;
    __syncthreads();
    #pragma unroll
    for (int kk = 0; kk < 16; kk++){
      float4 a = *(const float4*)&As[kk][ty*4];
      float4 b = *(const float4*)&Bs[kk][tx*4];
      float ar[4] = {a.x,a.y,a.z,a.w}, br[4] = {b.x,b.y,b.z,b.w};
      #pragma unroll
      for (int i=0;i<4;i++)
        #pragma unroll
        for (int j=0;j<4;j++)
          acc[i][j] += ar[i]*br[j];
    }
    __syncthreads();
  }
  #pragma unroll
  for (int i=0;i<4;i++){
    float4 o = make_float4(acc[i][0],acc[i][1],acc[i][2],acc[i][3]);
    *(float4*)(xz + (size_t)(mBase+ty*4+i)*1024 + nBase + tx*4) = o;
  }
}

// ---------- causal depthwise conv (w=4) + SiLU ----------
__global__ __launch_bounds__(256) void k_conv(const float* __restrict__ xz,
    const float* __restrict__ cw, const float* __restrict__ cb,
    float* __restrict__ uc){
  int g = blockIdx.x * 256 + threadIdx.x;
  int d = g & 511;
  int tok = g >> 9;
  int t = tok & (L_ - 1);
  float w0 = cw[d*4+0], w1 = cw[d*4+1], w2 = cw[d*4+2], w3 = cw[d*4+3];
  const float* up = xz + (size_t)tok * 1024 + d;
  float acc = cb[d] + w3 * up[0];
  if (t >= 1) acc += w2 * up[-1 * 1024];
  if (t >= 2) acc += w1 * up[-2 * 1024];
  if (t >= 3) acc += w0 * up[-3 * 1024];
  uc[g] = siluf_(acc);
}

// ---------- GEMM2: one output per thread; block = 320 thr; grid 1024 ----------
__global__ __launch_bounds__(320) void k_gemm2(const float* __restrict__ uc,
    const float* __restrict__ Wx, float* __restrict__ dbl){
  __shared__ float As[4 * 516];
  int tid = threadIdx.x;
  int mBase = blockIdx.x * 4;
  for (int idx = tid * 4; idx < 4 * 512; idx += 320 * 4){
    int r = idx >> 9, k = idx & 511;
    *(float4*)&As[r * 516 + k] = *(const float4*)(uc + (size_t)(mBase + r) * 512 + k);
  }
  __syncthreads();
  int n = tid >> 2;
  int r = tid & 3;
  const float* arow = &As[r * 516];
  const float* wp = Wx + (size_t)n * 512;
  float acc = 0.f;
  #pragma unroll 8
  for (int k4 = 0; k4 < 512; k4 += 4){
    float4 a = *(const float4*)&arow[k4];
    float4 w = *(const float4*)(wp + k4);
    acc += a.x*w.x + a.y*w.y + a.z*w.z + a.w*w.w;
  }
  dbl[(size_t)(mBase + r) * 80 + n] = acc;
}

// ---------- dt[m,d] = softplus(dbl[m,:16] . W_dt[d,:] + b_dt[d]) ----------
__global__ __launch_bounds__(256) void k_dt(const float* __restrict__ dbl,
    const float* __restrict__ Wdt, const float* __restrict__ bdt,
    float* __restrict__ dt){
  int g = blockIdx.x * 256 + threadIdx.x;
  int d = g & 511; int m = g >> 9;
  float acc = bdt[d];
  const float* r = dbl + (size_t)m * 80;
  #pragma unroll
  for (int k = 0; k < 16; k++)
    acc += r[k] * Wdt[d * 16 + k];
  dt[g] = softplusf_(acc);
}

// ---------- scan pass A: batch 4; lane owns 8 states of 1 channel; dual-path exp ----------
__global__ __launch_bounds__(256, 4) void k_scanA(const float* __restrict__ dt,
    const float* __restrict__ uc, const float* __restrict__ dbl,
    const float* __restrict__ A_log, const int* __restrict__ flagp,
    float* __restrict__ hseg, float* __restrict__ S){
  int gw   = (blockIdx.x * 256 + threadIdx.x) >> 6;
  int lane = threadIdx.x & 63;
  int dsub = lane & 7, ngrp = lane >> 3;
  int grp = gw & 255;
  int c   = gw >> 8;
  int ch  = grp * 8 + dsub;
  int b = ch >> 9, d = ch & 511;
  int fast = *flagp;
  const float* dtp = dt  + (size_t)b * L_ * 512 + d;
  const float* ucp = uc  + (size_t)b * L_ * 512 + d;
  const float* Bp  = dbl + (size_t)b * L_ * 80  + 16 + ngrp*8;
  float h[8] = {};
  float Ssum = 0.f;
  int tbeg = c * CL;
  float st1 = (float)(ngrp * 8 + 1);
  float Aa[8];
  if (!fast){
    float4 a0 = *(const float4*)(A_log + (size_t)d*64 + ngrp*8);
    float4 a1 = *(const float4*)(A_log + (size_t)d*64 + ngrp*8 + 4);
    Aa[0]=-__expf(a0.x); Aa[1]=-__expf(a0.y); Aa[2]=-__expf(a0.z); Aa[3]=-__expf(a0.w);
    Aa[4]=-__expf(a1.x); Aa[5]=-__expf(a1.y); Aa[6]=-__expf(a1.z); Aa[7]=-__expf(a1.w);
  }
  for (int t0 = tbeg; t0 < tbeg + CL; t0 += 4){
    float dt4[4], u4[4], Bv[4][8];
    #pragma unroll
    for (int j = 0; j < 4; j++){
      dt4[j] = dtp[(size_t)(t0+j) * 512];
      u4[j]  = ucp[(size_t)(t0+j) * 512];
      *(float4*)&Bv[j][0] = *(const float4*)(Bp + (size_t)(t0+j)*80);
      *(float4*)&Bv[j][4] = *(const float4*)(Bp + (size_t)(t0+j)*80 + 4);
    }
    if (fast){
      #pragma unroll
      for (int j = 0; j < 4; j++){
        float sc = dt4[j] * u4[j];
        Ssum += dt4[j];
        float e1 = __expf(-dt4[j]);
        float dA = __expf(-dt4[j] * st1);
        #pragma unroll
        for (int i = 0; i < 8; i++){
          h[i] = dA * h[i] + sc * Bv[j][i];
          dA *= e1;
        }
      }
    } else {
      #pragma unroll
      for (int j = 0; j < 4; j++){
        float sc = dt4[j] * u4[j];
        Ssum += dt4[j];
        #pragma unroll
        for (int i = 0; i < 8; i++)
          h[i] = __expf(dt4[j] * Aa[i]) * h[i] + sc * Bv[j][i];
      }
    }
  }
  float* hp = hseg + ((size_t)(c * 2048 + ch)) * 64 + ngrp*8;
  *(float4*)hp     = make_float4(h[0],h[1],h[2],h[3]);
  *(float4*)(hp+4) = make_float4(h[4],h[5],h[6],h[7]);
  if (ngrp == 0) S[c * 2048 + ch] = Ssum;
}

// ---------- scan pass B: sequential chunk combine, IN-PLACE ----------
__global__ __launch_bounds__(256) void k_scanB(float* __restrict__ hseg,
    const float* __restrict__ S, const float* __restrict__ A_log,
    const int* __restrict__ flagp){
  int ch   = (blockIdx.x * 256 + threadIdx.x) >> 6;
  int lane = threadIdx.x & 63;
  int d = ch & 511;
  int fast = *flagp;
  float A = fast ? -(float)(lane + 1) : -__expf(A_log[(size_t)d * 64 + lane]);
  float hc = 0.f;
  #pragma unroll
  for (int c = 0; c < NC; c++){
    size_t idx = ((size_t)(c * 2048 + ch)) * 64 + lane;
    float hf = hseg[idx];
    hseg[idx] = hc;
    float Sv = S[c * 2048 + ch];
    hc = hf + __expf(A * Sv) * hc;
  }
}

// ---------- scan pass C: fast path batch 4, generic batch 2; butterfly ----------
__global__ __launch_bounds__(256, 4) void k_scanC(const float* __restrict__ dt,
    const float* __restrict__ uc, const float* __restrict__ dbl,
    const float* __restrict__ C_SA, const float* __restrict__ A_log,
    const int* __restrict__ flagp,
    const float* __restrict__ hin, float* __restrict__ ys){
  int gw   = (blockIdx.x * 256 + threadIdx.x) >> 6;
  int lane = threadIdx.x & 63;
  int dsub = lane & 7, ngrp = lane >> 3;
  int grp = gw & 255;
  int c   = gw >> 8;
  int ch  = grp * 8 + dsub;
  int b = ch >> 9, d = ch & 511;
  int fast = *flagp;
  const float* dtp = dt   + (size_t)b * L_ * 512 + d;
  const float* ucp = uc   + (size_t)b * L_ * 512 + d;
  const float* Bp  = dbl  + (size_t)b * L_ * 80  + 16 + ngrp*8;
  const float* Cp  = C_SA + (size_t)b * L_ * 64  + ngrp*8;
  float*       yw  = ys   + (size_t)b * L_ * 512 + d;
  float h[8];
  {
    const float* hp = hin + ((size_t)(c * 2048 + ch)) * 64 + ngrp*8;
    float4 h0 = *(const float4*)hp;
    float4 h1 = *(const float4*)(hp + 4);
    h[0]=h0.x; h[1]=h0.y; h[2]=h0.z; h[3]=h0.w;
    h[4]=h1.x; h[5]=h1.y; h[6]=h1.z; h[7]=h1.w;
  }
  int tbeg = c * CL;
  float st1 = (float)(ngrp * 8 + 1);
  if (fast){
    for (int t0 = tbeg; t0 < tbeg + CL; t0 += 4){
      float dt4[4], u4[4], Bv[4][8], Cv[4][8];
      #pragma unroll
      for (int j = 0; j < 4; j++){
        dt4[j] = dtp[(size_t)(t0+j) * 512];
        u4[j]  = ucp[(size_t)(t0+j) * 512];
        *(float4*)&Bv[j][0] = *(const float4*)(Bp + (size_t)(t0+j)*80);
        *(float4*)&Bv[j][4] = *(const float4*)(Bp + (size_t)(t0+j)*80 + 4);
        *(float4*)&Cv[j][0] = *(const float4*)(Cp + (size_t)(t0+j)*64);
        *(float4*)&Cv[j][4] = *(const float4*)(Cp + (size_t)(t0+j)*64 + 4);
      }
      float yp[4];
      #pragma unroll
      for (int j = 0; j < 4; j++){
        float sc = dt4[j] * u4[j];
        float e1 = __expf(-dt4[j]);
        float dA = __expf(-dt4[j] * st1);
        float y = 0.f;
        #pragma unroll
        for (int i = 0; i < 8; i++){
          h[i] = dA * h[i] + sc * Bv[j][i];
          y += h[i] * Cv[j][i];
          dA *= e1;
        }
        yp[j] = y;
      }
      #pragma unroll
      for (int off = 8; off < 64; off <<= 1){
        #pragma unroll
        for (int j = 0; j < 4; j++)
          yp[j] += __shfl_xor(yp[j], off, 64);
      }
      if (ngrp == 0){
        #pragma unroll
        for (int j = 0; j < 4; j++)
          yw[(size_t)(t0+j) * 512] = yp[j];
      }
    }
  } else {
    float Aa[8];
    float4 a0 = *(const float4*)(A_log + (size_t)d*64 + ngrp*8);
    float4 a1 = *(const float4*)(A_log + (size_t)d*64 + ngrp*8 + 4);
    Aa[0]=-__expf(a0.x); Aa[1]=-__expf(a0.y); Aa[2]=-__expf(a0.z); Aa[3]=-__expf(a0.w);
    Aa[4]=-__expf(a1.x); Aa[5]=-__expf(a1.y); Aa[6]=-__expf(a1.z); Aa[7]=-__expf(a1.w);
    for (int t0 = tbeg; t0 < tbeg + CL; t0 += 2){
      float dt2[2], u2[2], Bv[2][8], Cv[2][8];
      #pragma unroll
      for (int j = 0; j < 2; j++){
        dt2[j] = dtp[(size_t)(t0+j) * 512];
        u2[j]  = ucp[(size_t)(t0+j) * 512];
        *(float4*)&Bv[j][0] = *(const float4*)(Bp + (size_t)(t0+j)*80);
        *(float4*)&Bv[j][4] = *(const float4*)(Bp + (size_t)(t0+j)*80 + 4);
        *(float4*)&Cv[j][0] = *(const float4*)(Cp + (size_t)(t0+j)*64);
        *(float4*)&Cv[j][4] = *(const float4*)(Cp + (size_t)(t0+j)*64 + 4);
      }
      float yp[2];
      #pragma unroll
      for (int j = 0; j < 2; j++){
        float sc = dt2[j] * u2[j];
        float y = 0.f;
        #pragma unroll
        for (int i = 0; i < 8; i++){
          h[i] = __expf(dt2[j] * Aa[i]) * h[i] + sc * Bv[j][i];
          y += h[i] * Cv[j][i];
        }
        yp[j] = y;
      }
      #pragma unroll
      for (int off = 8; off < 64; off <<= 1){
        #pragma unroll
        for (int j = 0; j < 2; j++)
          yp[j] += __shfl_xor(yp[j], off, 64);
      }
      if (ngrp == 0){
        yw[(size_t)(t0+0) * 512] = yp[0];
        yw[(size_t)(t0+1) * 512] = yp[1];
      }
    }
  }
}

// ---------- GEMM3 (gate fused): 64x64 tiles ----------
__global__ __launch_bounds__(256) void k_gemm3(const float* __restrict__ ys,
    const float* __restrict__ uc, const float* __restrict__ xz,
    const float* __restrict__ Dp, const float* __restrict__ Wout,
    float* __restrict__ out){
  __shared__ float As[16][64];
  __shared__ float Bs[16][64];
  int tid = threadIdx.x;
  int mBase = blockIdx.y * 64;
  int nBase = blockIdx.x * 64;
  int tx = tid & 15, ty = tid >> 4;
  int am = tid >> 2, ak = (tid & 3) << 2;
  float acc[4][4] = {};
  for (int kt = 0; kt < 512; kt += 16){
    int m = mBase + am;
    float4 yv = *(const float4*)(ys + (size_t)m*512 + kt + ak);
    float4 uv = *(const float4*)(uc + (size_t)m*512 + kt + ak);
    float4 zv = *(const float4*)(xz + (size_t)m*1024 + 512 + kt + ak);
    float4 dv = *(const float4*)(Dp + kt + ak);
    float4 bv = *(const float4*)(Wout + (size_t)(nBase+am)*512 + kt + ak);
    As[ak+0][am] = (yv.x + uv.x*dv.x) * siluf_(zv.x);
    As[ak+1][am] = (yv.y + uv.y*dv.y) * siluf_(zv.y);
    As[ak+2][am] = (yv.z + uv.z*dv.z) * siluf_(zv.z);
    As[ak+3][am] = (yv.w + uv.w*dv.w) * siluf_(zv.w);
    Bs[ak+0][am]=bv.x; Bs[ak+1][am]=bv.y; Bs[ak+2][am]=bv.z; Bs[ak+3][am]=bv.w;
    __syncthreads();
    #pragma unroll
    for (int kk=0;kk<16;kk++){
      float4 a = *(const float4*)&As[kk][ty*4];
      float4 b = *(const float4*)&Bs[kk][tx*4];
      float ar[4] = {a.x,a.y,a.z,a.w}, br[4] = {b.x,b.y,b.z,b.w};
      #pragma unroll
      for (int i=0;i<4;i++)
        #pragma unroll
        for (int j=0;j<4;j++)
          acc[i][j] += ar[i]*br[j];
    }
    __syncthreads();
  }
  #pragma unroll
  for (int i=0;i<4;i++){
    float4 o = make_float4(acc[i][0],acc[i][1],acc[i][2],acc[i][3]);
    *(float4*)(out + (size_t)(mBase+ty*4+i)*256 + nBase + tx*4) = o;
  }
}

extern "C" void kernel_launch(void* const* d_in, const int* in_sizes, int n_in,
                              void* d_out, int out_size, void* d_ws, size_t ws_size,
                              hipStream_t stream) {
  const float* x      = (const float*)d_in[0];
  const float* C_SA   = (const float*)d_in[1];
  const float* gamma  = (const float*)d_in[2];
  const float* beta   = (const float*)d_in[3];
  const float* W_in   = (const float*)d_in[4];
  const float* conv_w = (const float*)d_in[5];
  const float* conv_b = (const float*)d_in[6];
  const float* W_x    = (const float*)d_in[7];
  const float* W_dt   = (const float*)d_in[8];
  const float* b_dt   = (const float*)d_in[9];
  const float* A_log  = (const float*)d_in[10];
  const float* Dw     = (const float*)d_in[11];
  const float* W_out  = (const float*)d_in[12];
  float* out = (float*)d_out;

  float* ws    = (float*)d_ws;
  float* stats = ws;                        // 8192 used
  int*   flag  = (int*)(ws + 8192);
  float* xz    = ws    + 16384;             // 4194304
  float* uc    = xz    + 4194304;           // 2097152
  float* dbl   = uc    + 2097152;           // 327680
  float* dtb   = dbl   + 327680;            // 2097152
  float* hseg  = dtb   + 2097152;           // NC*131072 = 2097152 (doubles as hin)
  float* S     = hseg  + 2097152;           // 32768
  float* ysb   = S     + 32768;             // 2097152

  k_check<<<1, 1024, 0, stream>>>(A_log, flag);
  k_ln_stats<<<NTOK/4, 256, 0, stream>>>(x, stats);
  k_gemm1<<<dim3(16, 64), 256, 0, stream>>>(x, stats, gamma, beta, W_in, xz);
  k_conv <<<(NTOK*512)/256, 256, 0, stream>>>(xz, conv_w, conv_b, uc);
  k_gemm2<<<1024, 320, 0, stream>>>(uc, W_x, dbl);
  k_dt   <<<(NTOK*512)/256, 256, 0, stream>>>(dbl, W_dt, b_dt, dtb);
  k_scanA<<<NC*64, 256, 0, stream>>>(dtb, uc, dbl, A_log, flag, hseg, S);
  k_scanB<<<512, 256, 0, stream>>>(hseg, S, A_log, flag);
  k_scanC<<<NC*64, 256, 0, stream>>>(dtb, uc, dbl, C_SA, A_log, flag, hseg, ysb);
  k_gemm3<<<dim3(4, 64), 256, 0, stream>>>(ysb, uc, xz, Dw, W_out, out);
}